// Round 7
// baseline (2023.688 us; speedup 1.0000x reference)
//
#include <hip/hip_runtime.h>
#include <math.h>

// f32 I/O, f64 accumulation everywhere (bit-exact vs np-f64 ref at f32
// materialization points — absmax 0.0 in R4/R5/R6). Workspace 96 MiB:
// A(16,777,216 f32) + B(8,388,608 f32); boxes/scores live in dead x1 space.

constexpr int TOPK_N = 200;

// ---------------------------------------------------------------------------
// Tiled fused conv3x3(SAME)+bias+relu+maxpool2x2, f64 accumulators.
// Block = 256 threads = 16x16 pooled outputs (32x32 pre-pool), CO_BLK output
// channels per block, input staged in LDS per CI_BLK-channel chunk.
// R7: staging addresses precomputed ONCE per block (kills per-chunk div/mod).
// ---------------------------------------------------------------------------
template <int CIN, int CI_BLK, int CO_BLK>
__launch_bounds__(256)
__global__ void conv_relu_pool_tiled(const float* __restrict__ in,
                                     const float* __restrict__ wgt,
                                     const float* __restrict__ bias,
                                     float* __restrict__ out,
                                     int Hin, int Win, int Cout) {
    constexpr int TILE_ELEMS = CI_BLK * 34 * 34;
    constexpr int NSLOT = (TILE_ELEMS + 255) / 256;
    const int Hp = Hin >> 1, Wp = Win >> 1;
    const int coChunks = Cout / CO_BLK;
    const int b  = blockIdx.z / coChunks;
    const int cz = blockIdx.z % coChunks;
    const int tid = threadIdx.x;
    const int tx = tid & 15, ty = tid >> 4;
    const int px = (blockIdx.x << 4) + tx;
    const int py = (blockIdx.y << 4) + ty;
    const int iy0 = (blockIdx.y << 5) - 1;
    const int ix0 = (blockIdx.x << 5) - 1;

    __shared__ float  s_in[CI_BLK][34][34];
    __shared__ double s_w[CI_BLK * 9 * CO_BLK];
    float* s_in_flat = &s_in[0][0][0];

    // ---- precompute staging slots (per-block invariant across c0 chunks) ----
    int goff[NSLOT];  // global offset within (ci-rel, iy, ix); <0 => skip/zero
#pragma unroll
    for (int s = 0; s < NSLOT; ++s) {
        const int idx = tid + s * 256;
        int g = -1;
        if (idx < TILE_ELEMS) {
            const int ci = idx / (34 * 34);
            const int r  = idx - ci * 34 * 34;
            const int ly = r / 34, lx = r - ly * 34;
            const int iy = iy0 + ly, ix = ix0 + lx;
            if ((unsigned)iy < (unsigned)Hin && (unsigned)ix < (unsigned)Win)
                g = (ci * Hin + iy) * Win + ix;
        }
        goff[s] = g;
    }
    const float* in_b = in + (size_t)b * CIN * Hin * Win;

    double acc[CO_BLK][4];
#pragma unroll
    for (int co = 0; co < CO_BLK; ++co)
#pragma unroll
        for (int p = 0; p < 4; ++p) acc[co][p] = 0.0;

    for (int c0 = 0; c0 < CIN; c0 += CI_BLK) {
        const float* src = in_b + (size_t)c0 * Hin * Win;
        // stage input tile: add + load + select + ds_write per slot
#pragma unroll
        for (int s = 0; s < NSLOT; ++s) {
            const int idx = tid + s * 256;
            if (idx < TILE_ELEMS) {
                const int g = goff[s];
                float v = 0.f;
                if (g >= 0) v = src[g];
                s_in_flat[idx] = v;
            }
        }
        // stage weights (f64): s_w[(ci*9+k)*CO_BLK + co]
        for (int idx = tid; idx < CI_BLK * 9 * CO_BLK; idx += 256) {
            int co   = idx & (CO_BLK - 1);
            int rest = idx / CO_BLK;
            int k    = rest % 9;
            int ci   = rest / 9;
            s_w[idx] = (double)wgt[((cz * CO_BLK + co) * CIN + c0 + ci) * 9 + k];
        }
        __syncthreads();

#pragma unroll 1
        for (int ci = 0; ci < CI_BLK; ++ci) {
            double win[4][4];
#pragma unroll
            for (int iy = 0; iy < 4; ++iy) {
                float2 r0 = *(const float2*)&s_in[ci][2 * ty + iy][2 * tx];
                float2 r1 = *(const float2*)&s_in[ci][2 * ty + iy][2 * tx + 2];
                win[iy][0] = (double)r0.x; win[iy][1] = (double)r0.y;
                win[iy][2] = (double)r1.x; win[iy][3] = (double)r1.y;
            }
#pragma unroll
            for (int k = 0; k < 9; ++k) {
                const int ky = k / 3, kx = k % 3;
                const double* wp = &s_w[(ci * 9 + k) * CO_BLK];
                double w[CO_BLK];
#pragma unroll
                for (int co = 0; co < CO_BLK; ++co) w[co] = wp[co];
#pragma unroll
                for (int p = 0; p < 4; ++p) {
                    const double v = win[(p >> 1) + ky][(p & 1) + kx];
#pragma unroll
                    for (int co = 0; co < CO_BLK; ++co)
                        acc[co][p] = fma(v, w[co], acc[co][p]);
                }
            }
        }
        __syncthreads();
    }

#pragma unroll
    for (int co = 0; co < CO_BLK; ++co) {
        const double bd = (double)bias[cz * CO_BLK + co];
        const float e0 = fmaxf((float)(acc[co][0] + bd), 0.f);
        const float e1 = fmaxf((float)(acc[co][1] + bd), 0.f);
        const float e2 = fmaxf((float)(acc[co][2] + bd), 0.f);
        const float e3 = fmaxf((float)(acc[co][3] + bd), 0.f);
        out[((size_t)(b * Cout + cz * CO_BLK + co) * Hp + py) * Wp + px] =
            fmaxf(fmaxf(e0, e1), fmaxf(e2, e3));
    }
}

// ---------------------------------------------------------------------------
// Head 1x1 conv (256->5, f64) + decode (f64) -> boxes/scores. 32 blocks,
// one thread per cell, coalesced x4 reads.
// ---------------------------------------------------------------------------
__launch_bounds__(256)
__global__ void head_decode_k(const float* __restrict__ x4,
                              const float* __restrict__ wh,
                              const float* __restrict__ bh,
                              float* __restrict__ boxes,
                              float* __restrict__ scores) {
    __shared__ float s_wh[5 * 256];
    const int tid = threadIdx.x;
#pragma unroll
    for (int i = 0; i < 5; ++i) s_wh[i * 256 + tid] = wh[i * 256 + tid];
    __syncthreads();

    const int idx  = blockIdx.x * 256 + tid;  // 0..8191
    const int b    = idx >> 10;
    const int cell = idx & 1023;
    const int gy = cell >> 5, gx = cell & 31;

    double a0 = (double)bh[0], a1 = (double)bh[1], a2 = (double)bh[2],
           a3 = (double)bh[3], a4 = (double)bh[4];
    const float* xp = x4 + b * 262144 + cell;
    for (int ci = 0; ci < 256; ++ci) {
        const double v = (double)xp[ci << 10];
        a0 = fma(v, (double)s_wh[0 * 256 + ci], a0);
        a1 = fma(v, (double)s_wh[1 * 256 + ci], a1);
        a2 = fma(v, (double)s_wh[2 * 256 + ci], a2);
        a3 = fma(v, (double)s_wh[3 * 256 + ci], a3);
        a4 = fma(v, (double)s_wh[4 * 256 + ci], a4);
    }
    const double obj = 1.0 / (1.0 + exp(-a0));
    const double txs = 1.0 / (1.0 + exp(-a1));
    const double tys = 1.0 / (1.0 + exp(-a2));
    const double bw  = exp(a3) * 16.0;
    const double bhh = exp(a4) * 16.0;
    const double cx  = gx * 16.0 + txs * 16.0;
    const double cy  = gy * 16.0 + tys * 16.0;
    float* bp = boxes + idx * 4;
    bp[0] = (float)fmin(fmax(cx - bw * 0.5, 0.0), 511.0);
    bp[1] = (float)fmin(fmax(cy - bhh * 0.5, 0.0), 511.0);
    bp[2] = (float)fmin(fmax(cx + bw * 0.5, 0.0), 511.0);
    bp[3] = (float)fmin(fmax(cy + bhh * 0.5, 0.0), 511.0);
    scores[idx] = (float)obj;
}

// ---------------------------------------------------------------------------
// Per-batch top-200 (bitonic, lax.top_k tie semantics) + greedy NMS + output.
// ---------------------------------------------------------------------------
__launch_bounds__(256)
__global__ void topk_nms_k(const float* __restrict__ boxes,
                           const float* __restrict__ scores,
                           float* __restrict__ out5,
                           float* __restrict__ keep_out) {
    const int b = blockIdx.x, tid = threadIdx.x;
    __shared__ unsigned long long key[1024];
    __shared__ float bx1[TOPK_N], by1[TOPK_N], bx2[TOPK_N], by2[TOPK_N];
    __shared__ float sv[TOPK_N], ar[TOPK_N];
    __shared__ int   kp[TOPK_N];

    for (int i = tid; i < 1024; i += 256) {
        float s = scores[b * 1024 + i];
        float m = (s >= 0.01f) ? s : -1.0f;
        unsigned u = __float_as_uint(m);
        u = (u & 0x80000000u) ? ~u : (u | 0x80000000u);
        key[i] = ((unsigned long long)u << 32) | (unsigned)(1023 - i);
    }
    __syncthreads();

    for (int k = 2; k <= 1024; k <<= 1) {
        for (int j = k >> 1; j > 0; j >>= 1) {
            for (int i = tid; i < 1024; i += 256) {
                int l = i ^ j;
                if (l > i) {
                    unsigned long long a = key[i], c = key[l];
                    bool desc = ((i & k) == 0);
                    bool sw = desc ? (a < c) : (a > c);
                    if (sw) { key[i] = c; key[l] = a; }
                }
            }
            __syncthreads();
        }
    }

    for (int i = tid; i < TOPK_N; i += 256) {
        unsigned long long kk = key[i];
        unsigned u = (unsigned)(kk >> 32);
        unsigned bits = (u & 0x80000000u) ? (u & 0x7FFFFFFFu) : ~u;
        float s = __uint_as_float(bits);
        int src = 1023 - (int)(kk & 0xFFFFFFFFu);
        const float4 bb = *(const float4*)(boxes + (b * 1024 + src) * 4);
        bx1[i] = bb.x; by1[i] = bb.y; bx2[i] = bb.z; by2[i] = bb.w;
        sv[i] = s;
        ar[i] = (bb.z - bb.x) * (bb.w - bb.y);
        kp[i] = (s >= 0.01f) ? 1 : 0;
    }
    __syncthreads();

    for (int i = 0; i < TOPK_N; ++i) {
        if (kp[i]) {
            const float X1 = bx1[i], Y1 = by1[i], X2 = bx2[i], Y2 = by2[i], A = ar[i];
            for (int j = tid; j < TOPK_N; j += 256) {
                if (j > i && kp[j]) {
                    float xx1 = fmaxf(X1, bx1[j]);
                    float yy1 = fmaxf(Y1, by1[j]);
                    float xx2 = fminf(X2, bx2[j]);
                    float yy2 = fminf(Y2, by2[j]);
                    float inter = fmaxf(xx2 - xx1, 0.f) * fmaxf(yy2 - yy1, 0.f);
                    float uni = A + ar[j] - inter;
                    float iou = inter / fmaxf(uni, 1e-6f);
                    if (iou > 0.5f) kp[j] = 0;
                }
            }
        }
        __syncthreads();
    }

    for (int i = tid; i < TOPK_N; i += 256) {
        float kf = kp[i] ? 1.f : 0.f;
        float s  = sv[i];
        float sc = (s >= 0.01f) ? s : 0.f;
        float* op = out5 + (b * TOPK_N + i) * 5;
        op[0] = bx1[i] * kf;
        op[1] = by1[i] * kf;
        op[2] = bx2[i] * kf;
        op[3] = by2[i] * kf;
        op[4] = sc * kf;
        keep_out[b * TOPK_N + i] = kf;
    }
}

extern "C" void kernel_launch(void* const* d_in, const int* in_sizes, int n_in,
                              void* d_out, int out_size, void* d_ws, size_t ws_size,
                              hipStream_t stream) {
    const float* images = (const float*)d_in[0];
    const float* w1 = (const float*)d_in[1];
    const float* b1 = (const float*)d_in[2];
    const float* w2 = (const float*)d_in[3];
    const float* b2 = (const float*)d_in[4];
    const float* w3 = (const float*)d_in[5];
    const float* b3 = (const float*)d_in[6];
    const float* w4 = (const float*)d_in[7];
    const float* b4 = (const float*)d_in[8];
    const float* wh = (const float*)d_in[9];
    const float* bh = (const float*)d_in[10];
    float* out = (float*)d_out;

    float* A    = (float*)d_ws;          // x1 [8,32,256,256] -> x3 [8,128,64,64]
    float* Bbuf = A + 16777216;          // x2 [8,64,128,128] -> x4 [8,256,32,32]
    // boxes/scores: dead zone of A (x3 spans first 4.2M floats; x1 is dead)
    float* boxes  = A + 8388608;         // 32768 floats
    float* scores = A + 8388608 + 32768; //  8192 floats

    // L1: 3->32, 512x512 -> 256x256. 8192 blocks.
    conv_relu_pool_tiled<3, 3, 8><<<dim3(16, 16, 8 * 4), 256, 0, stream>>>(
        images, w1, b1, A, 512, 512, 32);
    // L2: 32->64, 256x256 -> 128x128. 4096 blocks.
    conv_relu_pool_tiled<32, 4, 8><<<dim3(8, 8, 8 * 8), 256, 0, stream>>>(
        A, w2, b2, Bbuf, 256, 256, 64);
    // L3: 64->128, 128x128 -> 64x64. 2048 blocks.
    conv_relu_pool_tiled<64, 4, 8><<<dim3(4, 4, 8 * 16), 256, 0, stream>>>(
        Bbuf, w3, b3, A, 128, 128, 128);
    // L4: 128->256, 64x64 -> 32x32. CO_BLK=8 (FMA density) -> 1024 blocks.
    conv_relu_pool_tiled<128, 4, 8><<<dim3(2, 2, 8 * 32), 256, 0, stream>>>(
        A, w4, b4, Bbuf, 64, 64, 256);
    // Head + decode: 32 blocks, coalesced
    head_decode_k<<<32, 256, 0, stream>>>(Bbuf, wh, bh, boxes, scores);
    // Top-k + NMS + output
    topk_nms_k<<<8, 256, 0, stream>>>(boxes, scores, out, out + 8 * TOPK_N * 5);
}

// Round 8
// 1501.792 us; speedup vs baseline: 1.3475x; 1.3475x over previous
//
#include <hip/hip_runtime.h>
#include <math.h>

// f32 I/O, f64 accumulation everywhere (bit-exact vs np-f64 ref at f32
// materialization points — absmax 0.0 R4-R7). Workspace 96 MiB:
// A(16,777,216 f32) + B(8,388,608 f32); boxes/scores in dead x1 space.
//
// R8: R6 structure + register-cheap staging (5 spatial offsets/thread,
// chunk-invariant; ci handled by pointer bump). R7's 19-reg goff array was an
// occupancy trap (VGPR 36->96, occ 55->21%) — do not reintroduce.

constexpr int TOPK_N = 200;

// ---------------------------------------------------------------------------
// Tiled fused conv3x3(SAME)+bias+relu+maxpool2x2, f64 accumulators.
// Block = 256 threads = 16x16 pooled outputs (32x32 pre-pool), CO_BLK output
// channels per block, input staged in LDS per CI_BLK-channel chunk.
// ---------------------------------------------------------------------------
template <int CIN, int CI_BLK, int CO_BLK>
__launch_bounds__(256)
__global__ void conv_relu_pool_tiled(const float* __restrict__ in,
                                     const float* __restrict__ wgt,
                                     const float* __restrict__ bias,
                                     float* __restrict__ out,
                                     int Hin, int Win, int Cout) {
    constexpr int SPATIAL = 34 * 34;               // 1156
    constexpr int SSLOT = (SPATIAL + 255) / 256;   // 5
    const int Hp = Hin >> 1, Wp = Win >> 1;
    const int coChunks = Cout / CO_BLK;
    const int b  = blockIdx.z / coChunks;
    const int cz = blockIdx.z % coChunks;
    const int tid = threadIdx.x;
    const int tx = tid & 15, ty = tid >> 4;
    const int px = (blockIdx.x << 4) + tx;
    const int py = (blockIdx.y << 4) + ty;
    const int iy0 = (blockIdx.y << 5) - 1;
    const int ix0 = (blockIdx.x << 5) - 1;

    __shared__ float  s_in[CI_BLK][34][34];
    __shared__ double s_w[CI_BLK * 9 * CO_BLK];
    float* s_in_flat = &s_in[0][0][0];

    // ---- 5 chunk-invariant spatial offsets per thread (cheap in regs) ----
    int soff[SSLOT];  // (iy*Win+ix) or -1 if out of image / past tile end
#pragma unroll
    for (int s = 0; s < SSLOT; ++s) {
        const int cell = tid + s * 256;
        int g = -1;
        if (cell < SPATIAL) {
            const int ly = cell / 34, lx = cell - ly * 34;
            const int iy = iy0 + ly, ix = ix0 + lx;
            if ((unsigned)iy < (unsigned)Hin && (unsigned)ix < (unsigned)Win)
                g = iy * Win + ix;
        }
        soff[s] = g;
    }
    const size_t HW = (size_t)Hin * Win;
    const float* in_b = in + (size_t)b * CIN * HW;

    double acc[CO_BLK][4];
#pragma unroll
    for (int co = 0; co < CO_BLK; ++co)
#pragma unroll
        for (int p = 0; p < 4; ++p) acc[co][p] = 0.0;

    for (int c0 = 0; c0 < CIN; c0 += CI_BLK) {
        // stage input tile: per ci, 5 slots of add+load+select+ds_write
#pragma unroll
        for (int ci = 0; ci < CI_BLK; ++ci) {
            const float* src = in_b + (c0 + ci) * HW;
#pragma unroll
            for (int s = 0; s < SSLOT; ++s) {
                const int cell = tid + s * 256;
                if (cell < SPATIAL) {
                    const int g = soff[s];
                    float v = 0.f;
                    if (g >= 0) v = src[g];
                    s_in_flat[ci * SPATIAL + cell] = v;
                }
            }
        }
        // stage weights (f64): s_w[(ci*9+k)*CO_BLK + co]
        for (int idx = tid; idx < CI_BLK * 9 * CO_BLK; idx += 256) {
            int co   = idx & (CO_BLK - 1);
            int rest = idx / CO_BLK;
            int k    = rest % 9;
            int ci   = rest / 9;
            s_w[idx] = (double)wgt[((cz * CO_BLK + co) * CIN + c0 + ci) * 9 + k];
        }
        __syncthreads();

#pragma unroll 1
        for (int ci = 0; ci < CI_BLK; ++ci) {
            double win[4][4];
#pragma unroll
            for (int iy = 0; iy < 4; ++iy) {
                float2 r0 = *(const float2*)&s_in[ci][2 * ty + iy][2 * tx];
                float2 r1 = *(const float2*)&s_in[ci][2 * ty + iy][2 * tx + 2];
                win[iy][0] = (double)r0.x; win[iy][1] = (double)r0.y;
                win[iy][2] = (double)r1.x; win[iy][3] = (double)r1.y;
            }
#pragma unroll
            for (int k = 0; k < 9; ++k) {
                const int ky = k / 3, kx = k % 3;
                const double* wp = &s_w[(ci * 9 + k) * CO_BLK];
                double w[CO_BLK];
#pragma unroll
                for (int co = 0; co < CO_BLK; ++co) w[co] = wp[co];
#pragma unroll
                for (int p = 0; p < 4; ++p) {
                    const double v = win[(p >> 1) + ky][(p & 1) + kx];
#pragma unroll
                    for (int co = 0; co < CO_BLK; ++co)
                        acc[co][p] = fma(v, w[co], acc[co][p]);
                }
            }
        }
        __syncthreads();
    }

#pragma unroll
    for (int co = 0; co < CO_BLK; ++co) {
        const double bd = (double)bias[cz * CO_BLK + co];
        const float e0 = fmaxf((float)(acc[co][0] + bd), 0.f);
        const float e1 = fmaxf((float)(acc[co][1] + bd), 0.f);
        const float e2 = fmaxf((float)(acc[co][2] + bd), 0.f);
        const float e3 = fmaxf((float)(acc[co][3] + bd), 0.f);
        out[((size_t)(b * Cout + cz * CO_BLK + co) * Hp + py) * Wp + px] =
            fmaxf(fmaxf(e0, e1), fmaxf(e2, e3));
    }
}

// ---------------------------------------------------------------------------
// Head 1x1 conv (256->5, f64) + decode (f64) -> boxes/scores. 32 blocks.
// ---------------------------------------------------------------------------
__launch_bounds__(256)
__global__ void head_decode_k(const float* __restrict__ x4,
                              const float* __restrict__ wh,
                              const float* __restrict__ bh,
                              float* __restrict__ boxes,
                              float* __restrict__ scores) {
    __shared__ float s_wh[5 * 256];
    const int tid = threadIdx.x;
#pragma unroll
    for (int i = 0; i < 5; ++i) s_wh[i * 256 + tid] = wh[i * 256 + tid];
    __syncthreads();

    const int idx  = blockIdx.x * 256 + tid;  // 0..8191
    const int b    = idx >> 10;
    const int cell = idx & 1023;
    const int gy = cell >> 5, gx = cell & 31;

    double a0 = (double)bh[0], a1 = (double)bh[1], a2 = (double)bh[2],
           a3 = (double)bh[3], a4 = (double)bh[4];
    const float* xp = x4 + b * 262144 + cell;
    for (int ci = 0; ci < 256; ++ci) {
        const double v = (double)xp[ci << 10];
        a0 = fma(v, (double)s_wh[0 * 256 + ci], a0);
        a1 = fma(v, (double)s_wh[1 * 256 + ci], a1);
        a2 = fma(v, (double)s_wh[2 * 256 + ci], a2);
        a3 = fma(v, (double)s_wh[3 * 256 + ci], a3);
        a4 = fma(v, (double)s_wh[4 * 256 + ci], a4);
    }
    const double obj = 1.0 / (1.0 + exp(-a0));
    const double txs = 1.0 / (1.0 + exp(-a1));
    const double tys = 1.0 / (1.0 + exp(-a2));
    const double bw  = exp(a3) * 16.0;
    const double bhh = exp(a4) * 16.0;
    const double cx  = gx * 16.0 + txs * 16.0;
    const double cy  = gy * 16.0 + tys * 16.0;
    float* bp = boxes + idx * 4;
    bp[0] = (float)fmin(fmax(cx - bw * 0.5, 0.0), 511.0);
    bp[1] = (float)fmin(fmax(cy - bhh * 0.5, 0.0), 511.0);
    bp[2] = (float)fmin(fmax(cx + bw * 0.5, 0.0), 511.0);
    bp[3] = (float)fmin(fmax(cy + bhh * 0.5, 0.0), 511.0);
    scores[idx] = (float)obj;
}

// ---------------------------------------------------------------------------
// Per-batch top-200 (bitonic, lax.top_k tie semantics) + greedy NMS + output.
// ---------------------------------------------------------------------------
__launch_bounds__(256)
__global__ void topk_nms_k(const float* __restrict__ boxes,
                           const float* __restrict__ scores,
                           float* __restrict__ out5,
                           float* __restrict__ keep_out) {
    const int b = blockIdx.x, tid = threadIdx.x;
    __shared__ unsigned long long key[1024];
    __shared__ float bx1[TOPK_N], by1[TOPK_N], bx2[TOPK_N], by2[TOPK_N];
    __shared__ float sv[TOPK_N], ar[TOPK_N];
    __shared__ int   kp[TOPK_N];

    for (int i = tid; i < 1024; i += 256) {
        float s = scores[b * 1024 + i];
        float m = (s >= 0.01f) ? s : -1.0f;
        unsigned u = __float_as_uint(m);
        u = (u & 0x80000000u) ? ~u : (u | 0x80000000u);
        key[i] = ((unsigned long long)u << 32) | (unsigned)(1023 - i);
    }
    __syncthreads();

    for (int k = 2; k <= 1024; k <<= 1) {
        for (int j = k >> 1; j > 0; j >>= 1) {
            for (int i = tid; i < 1024; i += 256) {
                int l = i ^ j;
                if (l > i) {
                    unsigned long long a = key[i], c = key[l];
                    bool desc = ((i & k) == 0);
                    bool sw = desc ? (a < c) : (a > c);
                    if (sw) { key[i] = c; key[l] = a; }
                }
            }
            __syncthreads();
        }
    }

    for (int i = tid; i < TOPK_N; i += 256) {
        unsigned long long kk = key[i];
        unsigned u = (unsigned)(kk >> 32);
        unsigned bits = (u & 0x80000000u) ? (u & 0x7FFFFFFFu) : ~u;
        float s = __uint_as_float(bits);
        int src = 1023 - (int)(kk & 0xFFFFFFFFu);
        const float4 bb = *(const float4*)(boxes + (b * 1024 + src) * 4);
        bx1[i] = bb.x; by1[i] = bb.y; bx2[i] = bb.z; by2[i] = bb.w;
        sv[i] = s;
        ar[i] = (bb.z - bb.x) * (bb.w - bb.y);
        kp[i] = (s >= 0.01f) ? 1 : 0;
    }
    __syncthreads();

    for (int i = 0; i < TOPK_N; ++i) {
        if (kp[i]) {
            const float X1 = bx1[i], Y1 = by1[i], X2 = bx2[i], Y2 = by2[i], A = ar[i];
            for (int j = tid; j < TOPK_N; j += 256) {
                if (j > i && kp[j]) {
                    float xx1 = fmaxf(X1, bx1[j]);
                    float yy1 = fmaxf(Y1, by1[j]);
                    float xx2 = fminf(X2, bx2[j]);
                    float yy2 = fminf(Y2, by2[j]);
                    float inter = fmaxf(xx2 - xx1, 0.f) * fmaxf(yy2 - yy1, 0.f);
                    float uni = A + ar[j] - inter;
                    float iou = inter / fmaxf(uni, 1e-6f);
                    if (iou > 0.5f) kp[j] = 0;
                }
            }
        }
        __syncthreads();
    }

    for (int i = tid; i < TOPK_N; i += 256) {
        float kf = kp[i] ? 1.f : 0.f;
        float s  = sv[i];
        float sc = (s >= 0.01f) ? s : 0.f;
        float* op = out5 + (b * TOPK_N + i) * 5;
        op[0] = bx1[i] * kf;
        op[1] = by1[i] * kf;
        op[2] = bx2[i] * kf;
        op[3] = by2[i] * kf;
        op[4] = sc * kf;
        keep_out[b * TOPK_N + i] = kf;
    }
}

extern "C" void kernel_launch(void* const* d_in, const int* in_sizes, int n_in,
                              void* d_out, int out_size, void* d_ws, size_t ws_size,
                              hipStream_t stream) {
    const float* images = (const float*)d_in[0];
    const float* w1 = (const float*)d_in[1];
    const float* b1 = (const float*)d_in[2];
    const float* w2 = (const float*)d_in[3];
    const float* b2 = (const float*)d_in[4];
    const float* w3 = (const float*)d_in[5];
    const float* b3 = (const float*)d_in[6];
    const float* w4 = (const float*)d_in[7];
    const float* b4 = (const float*)d_in[8];
    const float* wh = (const float*)d_in[9];
    const float* bh = (const float*)d_in[10];
    float* out = (float*)d_out;

    float* A    = (float*)d_ws;          // x1 [8,32,256,256] -> x3 [8,128,64,64]
    float* Bbuf = A + 16777216;          // x2 [8,64,128,128] -> x4 [8,256,32,32]
    float* boxes  = A + 8388608;         // dead x1 space: 32768 floats
    float* scores = A + 8388608 + 32768; //  8192 floats

    // L1: 3->32, 512x512 -> 256x256. 8192 blocks.
    conv_relu_pool_tiled<3, 3, 8><<<dim3(16, 16, 8 * 4), 256, 0, stream>>>(
        images, w1, b1, A, 512, 512, 32);
    // L2: 32->64, 256x256 -> 128x128. 4096 blocks.
    conv_relu_pool_tiled<32, 4, 8><<<dim3(8, 8, 8 * 8), 256, 0, stream>>>(
        A, w2, b2, Bbuf, 256, 256, 64);
    // L3: 64->128, 128x128 -> 64x64. 2048 blocks.
    conv_relu_pool_tiled<64, 4, 8><<<dim3(4, 4, 8 * 16), 256, 0, stream>>>(
        Bbuf, w3, b3, A, 128, 128, 128);
    // L4: 128->256, 64x64 -> 32x32. CO_BLK=8 -> 1024 blocks (4/CU).
    conv_relu_pool_tiled<128, 4, 8><<<dim3(2, 2, 8 * 32), 256, 0, stream>>>(
        A, w4, b4, Bbuf, 64, 64, 256);
    // Head + decode: 32 blocks, coalesced
    head_decode_k<<<32, 256, 0, stream>>>(Bbuf, wh, bh, boxes, scores);
    // Top-k + NMS + output
    topk_nms_k<<<8, 256, 0, stream>>>(boxes, scores, out, out + 8 * TOPK_N * 5);
}

// Round 9
// 1500.246 us; speedup vs baseline: 1.3489x; 1.0010x over previous
//
#include <hip/hip_runtime.h>
#include <math.h>

// f32 I/O, f64 accumulation everywhere (bit-exact vs np-f64 ref at f32
// materialization points — absmax 0.0 R4-R8). Workspace 96 MiB:
// A(16,777,216 f32) + B(8,388,608 f32); boxes/scores in dead x1 space.
//
// R9: CI_BLK=2 for L2-L4 -> LDS ~10.4 KB/block. Theory: workgroup LDS comes
// from a 64 KB pool (R8: 21 KB blocks capped at 3/CU = 63 KB); halving LDS
// should double blocks/CU. ci accumulation order unchanged -> still bit-exact.
// R7 lesson: no large per-thread address arrays (occupancy trap).

constexpr int TOPK_N = 200;

// ---------------------------------------------------------------------------
// Tiled fused conv3x3(SAME)+bias+relu+maxpool2x2, f64 accumulators.
// Block = 256 threads = 16x16 pooled outputs (32x32 pre-pool), CO_BLK output
// channels per block, input staged in LDS per CI_BLK-channel chunk.
// ---------------------------------------------------------------------------
template <int CIN, int CI_BLK, int CO_BLK>
__launch_bounds__(256)
__global__ void conv_relu_pool_tiled(const float* __restrict__ in,
                                     const float* __restrict__ wgt,
                                     const float* __restrict__ bias,
                                     float* __restrict__ out,
                                     int Hin, int Win, int Cout) {
    constexpr int SPATIAL = 34 * 34;               // 1156
    constexpr int SSLOT = (SPATIAL + 255) / 256;   // 5
    const int Hp = Hin >> 1, Wp = Win >> 1;
    const int coChunks = Cout / CO_BLK;
    const int b  = blockIdx.z / coChunks;
    const int cz = blockIdx.z % coChunks;
    const int tid = threadIdx.x;
    const int tx = tid & 15, ty = tid >> 4;
    const int px = (blockIdx.x << 4) + tx;
    const int py = (blockIdx.y << 4) + ty;
    const int iy0 = (blockIdx.y << 5) - 1;
    const int ix0 = (blockIdx.x << 5) - 1;

    __shared__ float  s_in[CI_BLK][34][34];
    __shared__ double s_w[CI_BLK * 9 * CO_BLK];
    float* s_in_flat = &s_in[0][0][0];

    // ---- chunk-invariant spatial offsets, 5 regs/thread ----
    int soff[SSLOT];  // (iy*Win+ix) or -1 if outside image / past tile end
#pragma unroll
    for (int s = 0; s < SSLOT; ++s) {
        const int cell = tid + s * 256;
        int g = -1;
        if (cell < SPATIAL) {
            const int ly = cell / 34, lx = cell - ly * 34;
            const int iy = iy0 + ly, ix = ix0 + lx;
            if ((unsigned)iy < (unsigned)Hin && (unsigned)ix < (unsigned)Win)
                g = iy * Win + ix;
        }
        soff[s] = g;
    }
    const size_t HW = (size_t)Hin * Win;
    const float* in_b = in + (size_t)b * CIN * HW;

    double acc[CO_BLK][4];
#pragma unroll
    for (int co = 0; co < CO_BLK; ++co)
#pragma unroll
        for (int p = 0; p < 4; ++p) acc[co][p] = 0.0;

    for (int c0 = 0; c0 < CIN; c0 += CI_BLK) {
        // stage input tile
#pragma unroll
        for (int ci = 0; ci < CI_BLK; ++ci) {
            const float* src = in_b + (c0 + ci) * HW;
#pragma unroll
            for (int s = 0; s < SSLOT; ++s) {
                const int cell = tid + s * 256;
                if (cell < SPATIAL) {
                    const int g = soff[s];
                    float v = 0.f;
                    if (g >= 0) v = src[g];
                    s_in_flat[ci * SPATIAL + cell] = v;
                }
            }
        }
        // stage weights (f64): s_w[(ci*9+k)*CO_BLK + co]
        for (int idx = tid; idx < CI_BLK * 9 * CO_BLK; idx += 256) {
            int co   = idx & (CO_BLK - 1);
            int rest = idx / CO_BLK;
            int k    = rest % 9;
            int ci   = rest / 9;
            s_w[idx] = (double)wgt[((cz * CO_BLK + co) * CIN + c0 + ci) * 9 + k];
        }
        __syncthreads();

#pragma unroll 1
        for (int ci = 0; ci < CI_BLK; ++ci) {
            double win[4][4];
#pragma unroll
            for (int iy = 0; iy < 4; ++iy) {
                float2 r0 = *(const float2*)&s_in[ci][2 * ty + iy][2 * tx];
                float2 r1 = *(const float2*)&s_in[ci][2 * ty + iy][2 * tx + 2];
                win[iy][0] = (double)r0.x; win[iy][1] = (double)r0.y;
                win[iy][2] = (double)r1.x; win[iy][3] = (double)r1.y;
            }
#pragma unroll
            for (int k = 0; k < 9; ++k) {
                const int ky = k / 3, kx = k % 3;
                const double* wp = &s_w[(ci * 9 + k) * CO_BLK];
                double w[CO_BLK];
#pragma unroll
                for (int co = 0; co < CO_BLK; ++co) w[co] = wp[co];
#pragma unroll
                for (int p = 0; p < 4; ++p) {
                    const double v = win[(p >> 1) + ky][(p & 1) + kx];
#pragma unroll
                    for (int co = 0; co < CO_BLK; ++co)
                        acc[co][p] = fma(v, w[co], acc[co][p]);
                }
            }
        }
        __syncthreads();
    }

#pragma unroll
    for (int co = 0; co < CO_BLK; ++co) {
        const double bd = (double)bias[cz * CO_BLK + co];
        const float e0 = fmaxf((float)(acc[co][0] + bd), 0.f);
        const float e1 = fmaxf((float)(acc[co][1] + bd), 0.f);
        const float e2 = fmaxf((float)(acc[co][2] + bd), 0.f);
        const float e3 = fmaxf((float)(acc[co][3] + bd), 0.f);
        out[((size_t)(b * Cout + cz * CO_BLK + co) * Hp + py) * Wp + px] =
            fmaxf(fmaxf(e0, e1), fmaxf(e2, e3));
    }
}

// ---------------------------------------------------------------------------
// Head 1x1 conv (256->5, f64) + decode (f64) -> boxes/scores. 32 blocks.
// ---------------------------------------------------------------------------
__launch_bounds__(256)
__global__ void head_decode_k(const float* __restrict__ x4,
                              const float* __restrict__ wh,
                              const float* __restrict__ bh,
                              float* __restrict__ boxes,
                              float* __restrict__ scores) {
    __shared__ float s_wh[5 * 256];
    const int tid = threadIdx.x;
#pragma unroll
    for (int i = 0; i < 5; ++i) s_wh[i * 256 + tid] = wh[i * 256 + tid];
    __syncthreads();

    const int idx  = blockIdx.x * 256 + tid;  // 0..8191
    const int b    = idx >> 10;
    const int cell = idx & 1023;
    const int gy = cell >> 5, gx = cell & 31;

    double a0 = (double)bh[0], a1 = (double)bh[1], a2 = (double)bh[2],
           a3 = (double)bh[3], a4 = (double)bh[4];
    const float* xp = x4 + b * 262144 + cell;
    for (int ci = 0; ci < 256; ++ci) {
        const double v = (double)xp[ci << 10];
        a0 = fma(v, (double)s_wh[0 * 256 + ci], a0);
        a1 = fma(v, (double)s_wh[1 * 256 + ci], a1);
        a2 = fma(v, (double)s_wh[2 * 256 + ci], a2);
        a3 = fma(v, (double)s_wh[3 * 256 + ci], a3);
        a4 = fma(v, (double)s_wh[4 * 256 + ci], a4);
    }
    const double obj = 1.0 / (1.0 + exp(-a0));
    const double txs = 1.0 / (1.0 + exp(-a1));
    const double tys = 1.0 / (1.0 + exp(-a2));
    const double bw  = exp(a3) * 16.0;
    const double bhh = exp(a4) * 16.0;
    const double cx  = gx * 16.0 + txs * 16.0;
    const double cy  = gy * 16.0 + tys * 16.0;
    float* bp = boxes + idx * 4;
    bp[0] = (float)fmin(fmax(cx - bw * 0.5, 0.0), 511.0);
    bp[1] = (float)fmin(fmax(cy - bhh * 0.5, 0.0), 511.0);
    bp[2] = (float)fmin(fmax(cx + bw * 0.5, 0.0), 511.0);
    bp[3] = (float)fmin(fmax(cy + bhh * 0.5, 0.0), 511.0);
    scores[idx] = (float)obj;
}

// ---------------------------------------------------------------------------
// Per-batch top-200 (bitonic, lax.top_k tie semantics) + greedy NMS + output.
// ---------------------------------------------------------------------------
__launch_bounds__(256)
__global__ void topk_nms_k(const float* __restrict__ boxes,
                           const float* __restrict__ scores,
                           float* __restrict__ out5,
                           float* __restrict__ keep_out) {
    const int b = blockIdx.x, tid = threadIdx.x;
    __shared__ unsigned long long key[1024];
    __shared__ float bx1[TOPK_N], by1[TOPK_N], bx2[TOPK_N], by2[TOPK_N];
    __shared__ float sv[TOPK_N], ar[TOPK_N];
    __shared__ int   kp[TOPK_N];

    for (int i = tid; i < 1024; i += 256) {
        float s = scores[b * 1024 + i];
        float m = (s >= 0.01f) ? s : -1.0f;
        unsigned u = __float_as_uint(m);
        u = (u & 0x80000000u) ? ~u : (u | 0x80000000u);
        key[i] = ((unsigned long long)u << 32) | (unsigned)(1023 - i);
    }
    __syncthreads();

    for (int k = 2; k <= 1024; k <<= 1) {
        for (int j = k >> 1; j > 0; j >>= 1) {
            for (int i = tid; i < 1024; i += 256) {
                int l = i ^ j;
                if (l > i) {
                    unsigned long long a = key[i], c = key[l];
                    bool desc = ((i & k) == 0);
                    bool sw = desc ? (a < c) : (a > c);
                    if (sw) { key[i] = c; key[l] = a; }
                }
            }
            __syncthreads();
        }
    }

    for (int i = tid; i < TOPK_N; i += 256) {
        unsigned long long kk = key[i];
        unsigned u = (unsigned)(kk >> 32);
        unsigned bits = (u & 0x80000000u) ? (u & 0x7FFFFFFFu) : ~u;
        float s = __uint_as_float(bits);
        int src = 1023 - (int)(kk & 0xFFFFFFFFu);
        const float4 bb = *(const float4*)(boxes + (b * 1024 + src) * 4);
        bx1[i] = bb.x; by1[i] = bb.y; bx2[i] = bb.z; by2[i] = bb.w;
        sv[i] = s;
        ar[i] = (bb.z - bb.x) * (bb.w - bb.y);
        kp[i] = (s >= 0.01f) ? 1 : 0;
    }
    __syncthreads();

    for (int i = 0; i < TOPK_N; ++i) {
        if (kp[i]) {
            const float X1 = bx1[i], Y1 = by1[i], X2 = bx2[i], Y2 = by2[i], A = ar[i];
            for (int j = tid; j < TOPK_N; j += 256) {
                if (j > i && kp[j]) {
                    float xx1 = fmaxf(X1, bx1[j]);
                    float yy1 = fmaxf(Y1, by1[j]);
                    float xx2 = fminf(X2, bx2[j]);
                    float yy2 = fminf(Y2, by2[j]);
                    float inter = fmaxf(xx2 - xx1, 0.f) * fmaxf(yy2 - yy1, 0.f);
                    float uni = A + ar[j] - inter;
                    float iou = inter / fmaxf(uni, 1e-6f);
                    if (iou > 0.5f) kp[j] = 0;
                }
            }
        }
        __syncthreads();
    }

    for (int i = tid; i < TOPK_N; i += 256) {
        float kf = kp[i] ? 1.f : 0.f;
        float s  = sv[i];
        float sc = (s >= 0.01f) ? s : 0.f;
        float* op = out5 + (b * TOPK_N + i) * 5;
        op[0] = bx1[i] * kf;
        op[1] = by1[i] * kf;
        op[2] = bx2[i] * kf;
        op[3] = by2[i] * kf;
        op[4] = sc * kf;
        keep_out[b * TOPK_N + i] = kf;
    }
}

extern "C" void kernel_launch(void* const* d_in, const int* in_sizes, int n_in,
                              void* d_out, int out_size, void* d_ws, size_t ws_size,
                              hipStream_t stream) {
    const float* images = (const float*)d_in[0];
    const float* w1 = (const float*)d_in[1];
    const float* b1 = (const float*)d_in[2];
    const float* w2 = (const float*)d_in[3];
    const float* b2 = (const float*)d_in[4];
    const float* w3 = (const float*)d_in[5];
    const float* b3 = (const float*)d_in[6];
    const float* w4 = (const float*)d_in[7];
    const float* b4 = (const float*)d_in[8];
    const float* wh = (const float*)d_in[9];
    const float* bh = (const float*)d_in[10];
    float* out = (float*)d_out;

    float* A    = (float*)d_ws;          // x1 [8,32,256,256] -> x3 [8,128,64,64]
    float* Bbuf = A + 16777216;          // x2 [8,64,128,128] -> x4 [8,256,32,32]
    float* boxes  = A + 8388608;         // dead x1 space: 32768 floats
    float* scores = A + 8388608 + 32768; //  8192 floats

    // L1: 3->32, 512x512 -> 256x256. LDS ~15.6 KB. 8192 blocks.
    conv_relu_pool_tiled<3, 3, 8><<<dim3(16, 16, 8 * 4), 256, 0, stream>>>(
        images, w1, b1, A, 512, 512, 32);
    // L2: 32->64. CI_BLK=2 -> ~10.4 KB LDS (6 blocks/CU under 64KB pool). 4096 blocks.
    conv_relu_pool_tiled<32, 2, 8><<<dim3(8, 8, 8 * 8), 256, 0, stream>>>(
        A, w2, b2, Bbuf, 256, 256, 64);
    // L3: 64->128. 2048 blocks.
    conv_relu_pool_tiled<64, 2, 8><<<dim3(4, 4, 8 * 16), 256, 0, stream>>>(
        Bbuf, w3, b3, A, 128, 128, 128);
    // L4: 128->256. 1024 blocks.
    conv_relu_pool_tiled<128, 2, 8><<<dim3(2, 2, 8 * 32), 256, 0, stream>>>(
        A, w4, b4, Bbuf, 64, 64, 256);
    // Head + decode: 32 blocks, coalesced
    head_decode_k<<<32, 256, 0, stream>>>(Bbuf, wh, bh, boxes, scores);
    // Top-k + NMS + output
    topk_nms_k<<<8, 256, 0, stream>>>(boxes, scores, out, out + 8 * TOPK_N * 5);
}

// Round 10
// 1341.251 us; speedup vs baseline: 1.5088x; 1.1185x over previous
//
#include <hip/hip_runtime.h>
#include <math.h>

// f32 I/O, f64 accumulation everywhere (bit-exact vs np-f64 ref at f32
// materialization points — absmax 0.0 R4-R9). Workspace 96 MiB:
// A(16,777,216 f32) + B(8,388,608 f32); boxes/scores in dead x1 space.
//
// R10: software-pipelined staging. Per chunk: prefetch next chunk's tile into
// registers (10 f32) -> compute current chunk (f64 FMA, ~2300 cy hides load
// latency) -> ds_write regs to the OTHER LDS buffer -> ONE barrier.
// R9 falsified the LDS-pool theory (occupancy invariant under LDS halving);
// occupancy is VGPR-capped (~140 real VGPRs: acc[8][4] f64 alone = 64) at
// ~3 blocks/CU, so latency must be hidden by ILP, not TLP.

constexpr int TOPK_N = 200;

// ---------------------------------------------------------------------------
// Tiled fused conv3x3(SAME)+bias+relu+maxpool2x2, f64 acc, pipelined staging.
// Block = 256 threads = 16x16 pooled outputs (32x32 pre-pool), CO_BLK=8.
// ---------------------------------------------------------------------------
template <int CIN, int CI_BLK, int CO_BLK>
__launch_bounds__(256)
__global__ void conv_relu_pool_pipe(const float* __restrict__ in,
                                    const float* __restrict__ wgt,
                                    const float* __restrict__ bias,
                                    float* __restrict__ out,
                                    int Hin, int Win, int Cout) {
    constexpr int SPATIAL = 34 * 34;               // 1156
    constexpr int SSLOT = (SPATIAL + 255) / 256;   // 5
    constexpr int NW = CI_BLK * 9 * CO_BLK;        // weights per chunk (144)
    constexpr int NCHUNK = CIN / CI_BLK;
    const int Hp = Hin >> 1, Wp = Win >> 1;
    const int coChunks = Cout / CO_BLK;
    const int b  = blockIdx.z / coChunks;
    const int cz = blockIdx.z % coChunks;
    const int tid = threadIdx.x;
    const int tx = tid & 15, ty = tid >> 4;
    const int px = (blockIdx.x << 4) + tx;
    const int py = (blockIdx.y << 4) + ty;
    const int iy0 = (blockIdx.y << 5) - 1;
    const int ix0 = (blockIdx.x << 5) - 1;

    __shared__ float  s_in[2][CI_BLK * SPATIAL];
    __shared__ double s_w[2][NW];

    // ---- chunk-invariant spatial offsets, 5 regs ----
    int soff[SSLOT];
#pragma unroll
    for (int s = 0; s < SSLOT; ++s) {
        const int cell = tid + s * 256;
        int g = -1;
        if (cell < SPATIAL) {
            const int ly = cell / 34, lx = cell - ly * 34;
            const int iy = iy0 + ly, ix = ix0 + lx;
            if ((unsigned)iy < (unsigned)Hin && (unsigned)ix < (unsigned)Win)
                g = iy * Win + ix;
        }
        soff[s] = g;
    }
    // ---- chunk-invariant weight slot (tid < NW handles one weight) ----
    int wg = -1;
    if (tid < NW) {
        const int co   = tid & (CO_BLK - 1);
        const int rest = tid / CO_BLK;
        const int k    = rest % 9;
        const int ci   = rest / 9;
        wg = ((cz * CO_BLK + co) * CIN + ci) * 9 + k;  // + c0*9 per chunk
    }
    const size_t HW = (size_t)Hin * Win;
    const float* in_b = in + (size_t)b * CIN * HW;

    double acc[CO_BLK][4];
#pragma unroll
    for (int co = 0; co < CO_BLK; ++co)
#pragma unroll
        for (int p = 0; p < 4; ++p) acc[co][p] = 0.0;

    float rin[CI_BLK][SSLOT];
    float rw = 0.f;

    // ---- prologue: fetch + commit chunk 0 ----
#pragma unroll
    for (int ci = 0; ci < CI_BLK; ++ci) {
        const float* src = in_b + ci * HW;
#pragma unroll
        for (int s = 0; s < SSLOT; ++s) {
            const int cell = tid + s * 256;
            float v = 0.f;
            if (cell < SPATIAL) { const int g = soff[s]; if (g >= 0) v = src[g]; }
            rin[ci][s] = v;
        }
    }
    if (tid < NW) rw = wgt[wg];
#pragma unroll
    for (int ci = 0; ci < CI_BLK; ++ci)
#pragma unroll
        for (int s = 0; s < SSLOT; ++s) {
            const int cell = tid + s * 256;
            if (cell < SPATIAL) s_in[0][ci * SPATIAL + cell] = rin[ci][s];
        }
    if (tid < NW) s_w[0][tid] = (double)rw;
    __syncthreads();

    for (int c = 0; c < NCHUNK; ++c) {
        const int buf = c & 1;
        // ---- issue next chunk's global loads (no wait; land under compute) ----
        if (c + 1 < NCHUNK) {
            const int c0n = (c + 1) * CI_BLK;
#pragma unroll
            for (int ci = 0; ci < CI_BLK; ++ci) {
                const float* src = in_b + (c0n + ci) * HW;
#pragma unroll
                for (int s = 0; s < SSLOT; ++s) {
                    const int cell = tid + s * 256;
                    float v = 0.f;
                    if (cell < SPATIAL) { const int g = soff[s]; if (g >= 0) v = src[g]; }
                    rin[ci][s] = v;
                }
            }
            if (tid < NW) rw = wgt[wg + c0n * 9];
        }
        // ---- compute current chunk from s_in[buf]/s_w[buf] ----
#pragma unroll 1
        for (int ci = 0; ci < CI_BLK; ++ci) {
            const float* tile = &s_in[buf][ci * SPATIAL];
            double win[4][4];
#pragma unroll
            for (int iy = 0; iy < 4; ++iy) {
                float2 r0 = *(const float2*)&tile[(2 * ty + iy) * 34 + 2 * tx];
                float2 r1 = *(const float2*)&tile[(2 * ty + iy) * 34 + 2 * tx + 2];
                win[iy][0] = (double)r0.x; win[iy][1] = (double)r0.y;
                win[iy][2] = (double)r1.x; win[iy][3] = (double)r1.y;
            }
#pragma unroll
            for (int k = 0; k < 9; ++k) {
                const int ky = k / 3, kx = k % 3;
                const double* wp = &s_w[buf][(ci * 9 + k) * CO_BLK];
                double w[CO_BLK];
#pragma unroll
                for (int co = 0; co < CO_BLK; ++co) w[co] = wp[co];
#pragma unroll
                for (int p = 0; p < 4; ++p) {
                    const double v = win[(p >> 1) + ky][(p & 1) + kx];
#pragma unroll
                    for (int co = 0; co < CO_BLK; ++co)
                        acc[co][p] = fma(v, w[co], acc[co][p]);
                }
            }
        }
        // ---- commit prefetched regs to the other buffer, one barrier ----
        if (c + 1 < NCHUNK) {
#pragma unroll
            for (int ci = 0; ci < CI_BLK; ++ci)
#pragma unroll
                for (int s = 0; s < SSLOT; ++s) {
                    const int cell = tid + s * 256;
                    if (cell < SPATIAL) s_in[buf ^ 1][ci * SPATIAL + cell] = rin[ci][s];
                }
            if (tid < NW) s_w[buf ^ 1][tid] = (double)rw;
            __syncthreads();
        }
    }

#pragma unroll
    for (int co = 0; co < CO_BLK; ++co) {
        const double bd = (double)bias[cz * CO_BLK + co];
        const float e0 = fmaxf((float)(acc[co][0] + bd), 0.f);
        const float e1 = fmaxf((float)(acc[co][1] + bd), 0.f);
        const float e2 = fmaxf((float)(acc[co][2] + bd), 0.f);
        const float e3 = fmaxf((float)(acc[co][3] + bd), 0.f);
        out[((size_t)(b * Cout + cz * CO_BLK + co) * Hp + py) * Wp + px] =
            fmaxf(fmaxf(e0, e1), fmaxf(e2, e3));
    }
}

// ---------------------------------------------------------------------------
// Head 1x1 conv (256->5, f64) + decode (f64) -> boxes/scores. 32 blocks.
// ---------------------------------------------------------------------------
__launch_bounds__(256)
__global__ void head_decode_k(const float* __restrict__ x4,
                              const float* __restrict__ wh,
                              const float* __restrict__ bh,
                              float* __restrict__ boxes,
                              float* __restrict__ scores) {
    __shared__ float s_wh[5 * 256];
    const int tid = threadIdx.x;
#pragma unroll
    for (int i = 0; i < 5; ++i) s_wh[i * 256 + tid] = wh[i * 256 + tid];
    __syncthreads();

    const int idx  = blockIdx.x * 256 + tid;  // 0..8191
    const int b    = idx >> 10;
    const int cell = idx & 1023;
    const int gy = cell >> 5, gx = cell & 31;

    double a0 = (double)bh[0], a1 = (double)bh[1], a2 = (double)bh[2],
           a3 = (double)bh[3], a4 = (double)bh[4];
    const float* xp = x4 + b * 262144 + cell;
    for (int ci = 0; ci < 256; ++ci) {
        const double v = (double)xp[ci << 10];
        a0 = fma(v, (double)s_wh[0 * 256 + ci], a0);
        a1 = fma(v, (double)s_wh[1 * 256 + ci], a1);
        a2 = fma(v, (double)s_wh[2 * 256 + ci], a2);
        a3 = fma(v, (double)s_wh[3 * 256 + ci], a3);
        a4 = fma(v, (double)s_wh[4 * 256 + ci], a4);
    }
    const double obj = 1.0 / (1.0 + exp(-a0));
    const double txs = 1.0 / (1.0 + exp(-a1));
    const double tys = 1.0 / (1.0 + exp(-a2));
    const double bw  = exp(a3) * 16.0;
    const double bhh = exp(a4) * 16.0;
    const double cx  = gx * 16.0 + txs * 16.0;
    const double cy  = gy * 16.0 + tys * 16.0;
    float* bp = boxes + idx * 4;
    bp[0] = (float)fmin(fmax(cx - bw * 0.5, 0.0), 511.0);
    bp[1] = (float)fmin(fmax(cy - bhh * 0.5, 0.0), 511.0);
    bp[2] = (float)fmin(fmax(cx + bw * 0.5, 0.0), 511.0);
    bp[3] = (float)fmin(fmax(cy + bhh * 0.5, 0.0), 511.0);
    scores[idx] = (float)obj;
}

// ---------------------------------------------------------------------------
// Per-batch top-200 (bitonic, lax.top_k tie semantics) + greedy NMS + output.
// ---------------------------------------------------------------------------
__launch_bounds__(256)
__global__ void topk_nms_k(const float* __restrict__ boxes,
                           const float* __restrict__ scores,
                           float* __restrict__ out5,
                           float* __restrict__ keep_out) {
    const int b = blockIdx.x, tid = threadIdx.x;
    __shared__ unsigned long long key[1024];
    __shared__ float bx1[TOPK_N], by1[TOPK_N], bx2[TOPK_N], by2[TOPK_N];
    __shared__ float sv[TOPK_N], ar[TOPK_N];
    __shared__ int   kp[TOPK_N];

    for (int i = tid; i < 1024; i += 256) {
        float s = scores[b * 1024 + i];
        float m = (s >= 0.01f) ? s : -1.0f;
        unsigned u = __float_as_uint(m);
        u = (u & 0x80000000u) ? ~u : (u | 0x80000000u);
        key[i] = ((unsigned long long)u << 32) | (unsigned)(1023 - i);
    }
    __syncthreads();

    for (int k = 2; k <= 1024; k <<= 1) {
        for (int j = k >> 1; j > 0; j >>= 1) {
            for (int i = tid; i < 1024; i += 256) {
                int l = i ^ j;
                if (l > i) {
                    unsigned long long a = key[i], c = key[l];
                    bool desc = ((i & k) == 0);
                    bool sw = desc ? (a < c) : (a > c);
                    if (sw) { key[i] = c; key[l] = a; }
                }
            }
            __syncthreads();
        }
    }

    for (int i = tid; i < TOPK_N; i += 256) {
        unsigned long long kk = key[i];
        unsigned u = (unsigned)(kk >> 32);
        unsigned bits = (u & 0x80000000u) ? (u & 0x7FFFFFFFu) : ~u;
        float s = __uint_as_float(bits);
        int src = 1023 - (int)(kk & 0xFFFFFFFFu);
        const float4 bb = *(const float4*)(boxes + (b * 1024 + src) * 4);
        bx1[i] = bb.x; by1[i] = bb.y; bx2[i] = bb.z; by2[i] = bb.w;
        sv[i] = s;
        ar[i] = (bb.z - bb.x) * (bb.w - bb.y);
        kp[i] = (s >= 0.01f) ? 1 : 0;
    }
    __syncthreads();

    for (int i = 0; i < TOPK_N; ++i) {
        if (kp[i]) {
            const float X1 = bx1[i], Y1 = by1[i], X2 = bx2[i], Y2 = by2[i], A = ar[i];
            for (int j = tid; j < TOPK_N; j += 256) {
                if (j > i && kp[j]) {
                    float xx1 = fmaxf(X1, bx1[j]);
                    float yy1 = fmaxf(Y1, by1[j]);
                    float xx2 = fminf(X2, bx2[j]);
                    float yy2 = fminf(Y2, by2[j]);
                    float inter = fmaxf(xx2 - xx1, 0.f) * fmaxf(yy2 - yy1, 0.f);
                    float uni = A + ar[j] - inter;
                    float iou = inter / fmaxf(uni, 1e-6f);
                    if (iou > 0.5f) kp[j] = 0;
                }
            }
        }
        __syncthreads();
    }

    for (int i = tid; i < TOPK_N; i += 256) {
        float kf = kp[i] ? 1.f : 0.f;
        float s  = sv[i];
        float sc = (s >= 0.01f) ? s : 0.f;
        float* op = out5 + (b * TOPK_N + i) * 5;
        op[0] = bx1[i] * kf;
        op[1] = by1[i] * kf;
        op[2] = bx2[i] * kf;
        op[3] = by2[i] * kf;
        op[4] = sc * kf;
        keep_out[b * TOPK_N + i] = kf;
    }
}

extern "C" void kernel_launch(void* const* d_in, const int* in_sizes, int n_in,
                              void* d_out, int out_size, void* d_ws, size_t ws_size,
                              hipStream_t stream) {
    const float* images = (const float*)d_in[0];
    const float* w1 = (const float*)d_in[1];
    const float* b1 = (const float*)d_in[2];
    const float* w2 = (const float*)d_in[3];
    const float* b2 = (const float*)d_in[4];
    const float* w3 = (const float*)d_in[5];
    const float* b3 = (const float*)d_in[6];
    const float* w4 = (const float*)d_in[7];
    const float* b4 = (const float*)d_in[8];
    const float* wh = (const float*)d_in[9];
    const float* bh = (const float*)d_in[10];
    float* out = (float*)d_out;

    float* A    = (float*)d_ws;          // x1 [8,32,256,256] -> x3 [8,128,64,64]
    float* Bbuf = A + 16777216;          // x2 [8,64,128,128] -> x4 [8,256,32,32]
    float* boxes  = A + 8388608;         // dead x1 space: 32768 floats
    float* scores = A + 8388608 + 32768; //  8192 floats

    // L1: 3->32, 512x512 -> 256x256. Single chunk (prologue only). 8192 blocks.
    conv_relu_pool_pipe<3, 3, 8><<<dim3(16, 16, 8 * 4), 256, 0, stream>>>(
        images, w1, b1, A, 512, 512, 32);
    // L2: 32->64. CI_BLK=2, pipelined. 4096 blocks.
    conv_relu_pool_pipe<32, 2, 8><<<dim3(8, 8, 8 * 8), 256, 0, stream>>>(
        A, w2, b2, Bbuf, 256, 256, 64);
    // L3: 64->128. 2048 blocks.
    conv_relu_pool_pipe<64, 2, 8><<<dim3(4, 4, 8 * 16), 256, 0, stream>>>(
        Bbuf, w3, b3, A, 128, 128, 128);
    // L4: 128->256. 1024 blocks.
    conv_relu_pool_pipe<128, 2, 8><<<dim3(2, 2, 8 * 32), 256, 0, stream>>>(
        A, w4, b4, Bbuf, 64, 64, 256);
    // Head + decode: 32 blocks, coalesced
    head_decode_k<<<32, 256, 0, stream>>>(Bbuf, wh, bh, boxes, scores);
    // Top-k + NMS + output
    topk_nms_k<<<8, 256, 0, stream>>>(boxes, scores, out, out + 8 * TOPK_N * 5);
}